// Round 4
// baseline (238.667 us; speedup 1.0000x reference)
//
#include <hip/hip_runtime.h>
#include <hip/hip_bf16.h>
#include <cstdint>

// ---------------------------------------------------------------------------
// Hamilton_V5  R13:
//  - launch3 (Hbwd grid + A3) byte-identical to R12 = CONTROL.
//    ...except hbwd64 inner loop now pipelined (see below) -- hbwd is 256 of
//    2304 blocks; A3 untouched.
//  - aw3t rewritten: 128x128 tiles (1024 blocks vs 16384), 16 float4
//    loads/thread, cvt_pk fp8 packing, u32-transposed LDS ([128][33] pad,
//    conflict-free drain), 128B coalesced u32 stores.
//  - gemm64 + hbwd64 K-loops: triple-buffered LDS, depth-2 prefetch,
//    counted vmcnt (A3's proven T4 pattern) -- one barrier per K-step,
//    no full drain (A2's 16 sequential round-trips were ~7 us/block).
// ---------------------------------------------------------------------------

typedef __bf16 bf16_t;
typedef __bf16 bf16x4_t __attribute__((ext_vector_type(4)));
typedef __bf16 bf16x8_t __attribute__((ext_vector_type(8)));
typedef float f32x4_t __attribute__((ext_vector_type(4)));
typedef float f32x16_t __attribute__((ext_vector_type(16)));
typedef int intx4_t __attribute__((ext_vector_type(4)));
typedef int intx8_t __attribute__((ext_vector_type(8)));

#define DIMD 128
#define NROW 4096
#define SMEM_G64 24576     // gemm64 3-buf (3*4096*2) ; aw3t 16896 fits
#define SMEM3_BYTES 73728  // a3: 3*(16384+8192); hbwd uses first 24576

// branchless tanh: t=2^(2x*log2e); tanh=1-2/(t+1).
__device__ __forceinline__ float fast_tanh(float x) {
  float t = __builtin_amdgcn_exp2f(x * 2.8853900817779268f);
  return 1.f - 2.f * __builtin_amdgcn_rcpf(t + 1.f);
}

// f32 -> fp8 e4m3 (OCP), RNE+sat via HW cvt
__device__ __forceinline__ uint8_t to_fp8(float x) {
  return (uint8_t)(__builtin_amdgcn_cvt_pk_fp8_f32(x, x, 0, false) & 0xff);
}

// pack 4 f32 -> 4 fp8 bytes (byte0=a .. byte3=d) via 2 HW cvt_pk
__device__ __forceinline__ uint32_t pk4_fp8(float a, float b, float c,
                                            float d) {
  uint32_t lo = (uint32_t)__builtin_amdgcn_cvt_pk_fp8_f32(a, b, 0, false);
  return (uint32_t)__builtin_amdgcn_cvt_pk_fp8_f32(c, d, lo, true);
}

// async global->LDS, 16B per lane; LDS dest = wave-uniform base + lane*16
__device__ __forceinline__ void g2l16(const void* gp, void* lp) {
  __builtin_amdgcn_global_load_lds(
      reinterpret_cast<__attribute__((address_space(1))) void*>(
          reinterpret_cast<uintptr_t>(gp)),
      reinterpret_cast<__attribute__((address_space(3))) void*>(
          reinterpret_cast<uintptr_t>(lp)),
      16, 0, 0);
}

// DPP accumulating add (VALU pipe -- no LDS). bound_ctrl=1 => 0-fill.
template <int CTRL>
__device__ __forceinline__ float dpp_addf(float v) {
  return v + __int_as_float(__builtin_amdgcn_update_dpp(
                 0, __float_as_int(v), CTRL, 0xf, 0xf, true));
}
// sum over each 32-lane half; result in lane 31 (half 0) / lane 63 (half 1).
__device__ __forceinline__ float dpp_sum32(float v) {
  v = dpp_addf<0x111>(v);  // row_shr:1
  v = dpp_addf<0x112>(v);  // row_shr:2
  v = dpp_addf<0x114>(v);  // row_shr:4
  v = dpp_addf<0x118>(v);  // row_shr:8  -> lane15/31/47/63 = row sums
  v = dpp_addf<0x142>(v);  // row_bcast15 -> lane31/63 = 32-lane sums
  return v;
}

// ---------------------------------------------------------------------------
// bf16 GEMM, 64x64 tile, BK=32, 4 waves 2x2 (each 32x32 = 2x2 mfma 16x16x32).
// R13: triple-buffered LDS, depth-2 prefetch, counted vmcnt(2) per step.
// LDS swizzle: row r's 16B k-chunk kc at slot kc ^ ((r>>1)&3).
// EPI 0: bf16 tanh(C+b); EPI 3: fp8 x64.  (256-thread launches only.)
// ---------------------------------------------------------------------------
template <int EPI>
__device__ __forceinline__ void gemm64_body(char* smem, int bx, int by,
                                            const bf16_t* A, int lda,
                                            const bf16_t* B, int ldb, int K,
                                            const float* bias, void* outp,
                                            int ldo) {
  constexpr int BK = 32;
  bf16_t* As = (bf16_t*)smem;   // 3 x 64*32
  bf16_t* Bs = As + 3 * 2048;   // 3 x 64*32
  const int NT = K / BK;

  const int m0 = bx * 64;
  const int n0 = by * 64;
  const int tid = threadIdx.x;
  const int wave = tid >> 6;
  const int lane = tid & 63;
  const int wm = wave >> 1;
  const int wn = wave & 1;

  const int sr = lane >> 2;
  const int sk = (((lane & 3) ^ ((sr >> 1) & 3)) * 8);
  const int fr = lane & 15;
  const int fk = (((lane >> 4) ^ ((fr >> 1) & 3)) * 8);
  const int rb = wave * 16;  // each wave stages 16 rows of A and B

  const bf16_t* Ag = A + (size_t)(m0 + rb + sr) * lda + sk;
  const bf16_t* Bg = B + (size_t)(n0 + rb + sr) * ldb + sk;

#define G64_STAGE(buf, k0)                              \
  do {                                                  \
    g2l16(Ag + (k0), As + (buf) * 2048 + rb * BK);      \
    g2l16(Bg + (k0), Bs + (buf) * 2048 + rb * BK);      \
  } while (0)

  f32x4_t acc[2][2] = {};

  G64_STAGE(0, 0);
  G64_STAGE(1, BK);
  asm volatile("s_waitcnt vmcnt(2)" ::: "memory");
  __builtin_amdgcn_s_barrier();
  asm volatile("" ::: "memory");

  for (int t = 0; t < NT; ++t) {
    if (t + 2 < NT) G64_STAGE((t + 2) % 3, (t + 2) * BK);
    const bf16_t* Ab = As + (t % 3) * 2048;
    const bf16_t* Bb = Bs + (t % 3) * 2048;

    bf16x8_t af[2], bb[2];
#pragma unroll
    for (int u = 0; u < 2; ++u) {
      af[u] = *(const bf16x8_t*)(Ab + (wm * 32 + u * 16 + fr) * BK + fk);
      bb[u] = *(const bf16x8_t*)(Bb + (wn * 32 + u * 16 + fr) * BK + fk);
    }
#pragma unroll
    for (int i = 0; i < 2; ++i)
#pragma unroll
      for (int j = 0; j < 2; ++j)
        acc[i][j] = __builtin_amdgcn_mfma_f32_16x16x32_bf16(af[i], bb[j],
                                                            acc[i][j], 0, 0, 0);
    if (t < NT - 1) {
      if (t + 2 < NT)
        asm volatile("s_waitcnt vmcnt(2)" ::: "memory");
      else
        asm volatile("s_waitcnt vmcnt(0)" ::: "memory");
      __builtin_amdgcn_s_barrier();
      asm volatile("" ::: "memory");
    }
  }
#undef G64_STAGE

  // C/D layout (m89): col = lane&15, row = (lane>>4)*4 + reg
#pragma unroll
  for (int i = 0; i < 2; ++i) {
    const int row = m0 + wm * 32 + i * 16 + (lane >> 4) * 4;
#pragma unroll
    for (int j = 0; j < 2; ++j) {
      const int col = n0 + wn * 32 + j * 16 + fr;
      if constexpr (EPI == 0) {
        bf16_t* O = (bf16_t*)outp;
        const float b = bias[col];
#pragma unroll
        for (int r = 0; r < 4; ++r)
          O[(size_t)(row + r) * ldo + col] = (bf16_t)fast_tanh(acc[i][j][r] + b);
      } else {  // EPI 3
        uint8_t* O = (uint8_t*)outp;
        const float b = bias[col];
#pragma unroll
        for (int r = 0; r < 4; ++r)
          O[(size_t)(row + r) * ldo + col] =
              to_fp8(64.f * fast_tanh(acc[i][j][r] + b));
      }
    }
  }
}

// ---------------------------------------------------------------------------
// Hbwd bf16 GEMM for 512-thread launch: 64x64 tile, BK=32, 8 waves arranged
// 2x4; per-wave 32x16 = 2x1 mfma 16x16x32.  dx store / dv atomicAdd(-C).
// R13: same triple-buffer/counted-vmcnt pipeline (1 stage op per wave).
// ---------------------------------------------------------------------------
__device__ __forceinline__ void hbwd64_body(char* smem, int bx, int by,
                                            const bf16_t* A, int lda,
                                            const bf16_t* B, int ldb, int K,
                                            float* out, int ldo) {
  constexpr int BK = 32;
  bf16_t* As = (bf16_t*)smem;  // 3 x 64*32
  bf16_t* Bs = As + 3 * 2048;
  const int NT = K / BK;  // 20

  const int m0 = bx * 64;
  const int n0 = by * 64;
  const int tid = threadIdx.x;
  const int wave = tid >> 6;  // 0..7
  const int lane = tid & 63;
  const int wm = wave >> 2;   // 0..1
  const int wn = wave & 3;    // 0..3

  const int sr = lane >> 2;
  const int sk = (((lane & 3) ^ ((sr >> 1) & 3)) * 8);
  const int fr = lane & 15;
  const int fk = (((lane >> 4) ^ ((fr >> 1) & 3)) * 8);

  // waves 0..3 stage A rows, 4..7 stage B rows (1 g2l16 per wave per step)
  const int rbs = (wave & 3) * 16;
  const bf16_t* Sg = (wave < 4) ? A + (size_t)(m0 + rbs + sr) * lda + sk
                                : B + (size_t)(n0 + rbs + sr) * ldb + sk;
  bf16_t* Sl = ((wave < 4) ? As : Bs) + rbs * BK;

  f32x4_t acc[2] = {};

  g2l16(Sg, Sl);
  g2l16(Sg + BK, Sl + 2048);
  asm volatile("s_waitcnt vmcnt(1)" ::: "memory");
  __builtin_amdgcn_s_barrier();
  asm volatile("" ::: "memory");

  for (int t = 0; t < NT; ++t) {
    if (t + 2 < NT) g2l16(Sg + (t + 2) * BK, Sl + ((t + 2) % 3) * 2048);
    const bf16_t* Ab = As + (t % 3) * 2048;
    const bf16_t* Bb = Bs + (t % 3) * 2048;

    const bf16x8_t bb = *(const bf16x8_t*)(Bb + (wn * 16 + fr) * BK + fk);
#pragma unroll
    for (int u = 0; u < 2; ++u) {
      const bf16x8_t af =
          *(const bf16x8_t*)(Ab + (wm * 32 + u * 16 + fr) * BK + fk);
      acc[u] = __builtin_amdgcn_mfma_f32_16x16x32_bf16(af, bb, acc[u], 0, 0, 0);
    }
    if (t < NT - 1) {
      if (t + 2 < NT)
        asm volatile("s_waitcnt vmcnt(1)" ::: "memory");
      else
        asm volatile("s_waitcnt vmcnt(0)" ::: "memory");
      __builtin_amdgcn_s_barrier();
      asm volatile("" ::: "memory");
    }
  }

  // C/D layout (m89): col = lane&15, row = (lane>>4)*4 + reg
  const bool dx = (n0 < DIMD);
  const int col = n0 + wn * 16 + fr;
#pragma unroll
  for (int t = 0; t < 2; ++t) {
    const int row = m0 + wm * 32 + t * 16 + (lane >> 4) * 4;
#pragma unroll
    for (int r = 0; r < 4; ++r) {
      const size_t idx = (size_t)(row + r) * ldo + col;
      if (dx) out[idx] = acc[t][r];
      else atomicAdd(&out[idx], -acc[t][r]);  // dv_H shares with dvA
    }
  }
}

// ---------------------------------------------------------------------------
// A3 fused GEMM, MX-fp8 (R12, UNCHANGED = control): 512 threads / 8 waves,
// BM=256, BN=128, BK=64; triple-buffer, counted vmcnt(3), setprio, DPP epi.
// ---------------------------------------------------------------------------
__device__ __forceinline__ void a3_body(char* smem, int bx, int by,
                                        const uint8_t* A, const uint8_t* B,
                                        float* out, const float* ab3,
                                        const float* uvec) {
  constexpr int BK = 64, K = 1024, NT = K / BK;  // NT = 16
  uint8_t* As = (uint8_t*)smem;             // 3 x 256*64 = 49152
  uint8_t* Bs = As + 49152;                 // 3 x 128*64 = 24576

  const int m0 = bx * 256;
  const int n0 = by * 128;
  const int tid = threadIdx.x;
  const int wave = tid >> 6;  // 0..7
  const int lane = tid & 63;
  const int wm = wave >> 1;   // 0..3 : 64-row strip
  const int wn = wave & 1;    // 0..1 : 64-col strip

  const int sr = lane >> 2;
  const int sk = ((lane & 3) ^ ((sr >> 1) & 3)) * 16;

  const int rl = lane & 31;
  const int w = (rl >> 1) & 3;
  const int c0 = lane >> 5;
  const int sLo = ((2 * c0) ^ w) * 16;
  const int sHi = ((2 * c0 + 1) ^ w) * 16;

  f32x16_t acc[2][2] = {};

#define A3_STAGE(buf, k0)                                                     \
  do {                                                                        \
    uint8_t* Ad = As + (buf) * 16384;                                         \
    uint8_t* Bd = Bs + (buf) * 8192;                                          \
    _Pragma("unroll") for (int t_ = 0; t_ < 2; ++t_) {                        \
      const int rb_ = wave * 32 + t_ * 16;                                    \
      g2l16(A + (size_t)(m0 + rb_ + sr) * K + ((k0) + sk), Ad + rb_ * BK);    \
    }                                                                         \
    const int rbB_ = wave * 16;                                               \
    g2l16(B + (size_t)(n0 + rbB_ + sr) * K + ((k0) + sk), Bd + rbB_ * BK);    \
  } while (0)

  A3_STAGE(0, 0);
  A3_STAGE(1, BK);
  asm volatile("s_waitcnt vmcnt(3)" ::: "memory");
  __builtin_amdgcn_s_barrier();
  asm volatile("" ::: "memory");

  int cur = 0, pre = 2;
#pragma unroll 1
  for (int t = 0; t < NT; ++t) {
    if (t + 2 < NT) A3_STAGE(pre, (t + 2) * BK);
    const uint8_t* Ab = As + cur * 16384;
    const uint8_t* Bb = Bs + cur * 8192;

    __builtin_amdgcn_s_setprio(1);
    intx8_t bfr[2];
#pragma unroll
    for (int j = 0; j < 2; ++j) {
      const int rb2 = (wn * 64 + j * 32 + rl) * BK;
      intx4_t lob = *(const intx4_t*)(Bb + rb2 + sLo);
      intx4_t hib = *(const intx4_t*)(Bb + rb2 + sHi);
      bfr[j] = __builtin_shufflevector(lob, hib, 0, 1, 2, 3, 4, 5, 6, 7);
    }
#pragma unroll
    for (int i = 0; i < 2; ++i) {
      const int ra = (wm * 64 + i * 32 + rl) * BK;
      intx4_t lo = *(const intx4_t*)(Ab + ra + sLo);
      intx4_t hi = *(const intx4_t*)(Ab + ra + sHi);
      intx8_t af = __builtin_shufflevector(lo, hi, 0, 1, 2, 3, 4, 5, 6, 7);
#pragma unroll
      for (int j = 0; j < 2; ++j)
        acc[i][j] = __builtin_amdgcn_mfma_scale_f32_32x32x64_f8f6f4(
            af, bfr[j], acc[i][j], 0, 0, 0, 0x79797979, 0, 0x79797979);
    }
    __builtin_amdgcn_s_setprio(0);

    if (t < NT - 1) {
      if (t + 2 < NT)
        asm volatile("s_waitcnt vmcnt(3)" ::: "memory");
      else
        asm volatile("s_waitcnt vmcnt(0)" ::: "memory");
      __builtin_amdgcn_s_barrier();
      asm volatile("" ::: "memory");
    }
    cur = (cur == 2) ? 0 : cur + 1;
    pre = (pre == 2) ? 0 : pre + 1;
  }
#undef A3_STAGE

  // epilogue: no LDS. C/D: col = lane&31, row = (reg&3)+8*(reg>>2)+4*(lane>>5)
  const int q = lane >> 5;
  const int cA = wn * 64 + rl;
  const float uu0 = uvec[cA];
  const float uu1 = uvec[cA + 32];
  const float b30 = ab3[n0 + cA];
  const float b31 = ab3[n0 + cA + 32];
#pragma unroll
  for (int i = 0; i < 2; ++i) {
    float s16[16];
#pragma unroll
    for (int r = 0; r < 16; ++r)
      s16[r] = fast_tanh(acc[i][0][r] + b30) * uu0 +
               fast_tanh(acc[i][1][r] + b31) * uu1;
#pragma unroll
    for (int r = 0; r < 16; ++r) s16[r] = dpp_sum32(s16[r]);
    if (rl == 31) {  // lanes 31 and 63 hold the two half-sums
      const int rowb = m0 + wm * 64 + i * 32 + 4 * q;
#pragma unroll
      for (int r = 0; r < 16; ++r)
        atomicAdd(
            &out[(size_t)(rowb + (r & 3) + 8 * (r >> 2)) * 256 + 128 + by],
            s16[r]);
    }
  }
}

// ---------------------------------------------------------------------------
// transposes / cvt helpers
// ---------------------------------------------------------------------------
__device__ __forceinline__ void tcvt_body(char* smem, const float* in,
                                          bf16_t* out, int R, int C, int bx,
                                          int by) {
  float(*t)[33] = (float(*)[33])smem;  // 4224 B
  const int c0 = bx * 32;
  const int r0 = by * 32;
  const int tx = threadIdx.x & 31;
  const int ty = threadIdx.x >> 5;
#pragma unroll
  for (int k = 0; k < 4; ++k)
    t[ty + k * 8][tx] = in[(size_t)(r0 + ty + k * 8) * C + c0 + tx];
  __syncthreads();
#pragma unroll
  for (int k = 0; k < 4; ++k)
    out[(size_t)(c0 + ty + k * 8) * R + r0 + tx] = (bf16_t)t[tx][ty + k * 8];
}

// Aw3 (1024 x 16384) -> fp8 x64, transposed (16384 x 1024).
// R13: 128x128 tile per block (1024 blocks total), float4 reads, cvt_pk
// packing, u32-transposed LDS [128][33] (pad -> conflict-free drain),
// 128B-coalesced u32 stores.  b in [0,1024): rt=b>>7 (row tile), ct=b&127.
__device__ __forceinline__ void aw3t_body(char* smem, const float* Aw3,
                                          uint8_t* Aw3T8, int b) {
  uint32_t(*T)[33] = (uint32_t(*)[33])smem;  // 16896 B
  const int ct = b & 127;
  const int rt = b >> 7;
  const size_t c0 = (size_t)ct * 128;
  const int r0 = rt * 128;
  const int tx = threadIdx.x & 31;  // col-chunk (4 f32)
  const int g = threadIdx.x >> 5;   // 0..7 row-group
#pragma unroll
  for (int k = 0; k < 4; ++k) {
    const int rr = r0 + 4 * g + 32 * k;
    const float4 v0 = *(const float4*)(Aw3 + (size_t)(rr + 0) * 16384 + c0 + 4 * tx);
    const float4 v1 = *(const float4*)(Aw3 + (size_t)(rr + 1) * 16384 + c0 + 4 * tx);
    const float4 v2 = *(const float4*)(Aw3 + (size_t)(rr + 2) * 16384 + c0 + 4 * tx);
    const float4 v3 = *(const float4*)(Aw3 + (size_t)(rr + 3) * 16384 + c0 + 4 * tx);
    const int r4 = g + 8 * k;  // row/4 within tile
    T[4 * tx + 0][r4] = pk4_fp8(64.f * v0.x, 64.f * v1.x, 64.f * v2.x, 64.f * v3.x);
    T[4 * tx + 1][r4] = pk4_fp8(64.f * v0.y, 64.f * v1.y, 64.f * v2.y, 64.f * v3.y);
    T[4 * tx + 2][r4] = pk4_fp8(64.f * v0.z, 64.f * v1.z, 64.f * v2.z, 64.f * v3.z);
    T[4 * tx + 3][r4] = pk4_fp8(64.f * v0.w, 64.f * v1.w, 64.f * v2.w, 64.f * v3.w);
  }
  __syncthreads();
#pragma unroll
  for (int k2 = 0; k2 < 16; ++k2) {
    const int cc = g + 8 * k2;  // output row (Aw3 col)
    *(uint32_t*)(Aw3T8 + (c0 + cc) * 1024 + r0 + 4 * tx) = T[cc][tx];
  }
}

// one wave handles one row: pre2 = h.Hw2; w_j = s*Hw2_j*(1-h_j^2)
__device__ __forceinline__ void hgrad_row(int row, const bf16_t* h,
                                          const float* Hw2, const float* Hb2,
                                          bf16_t* wout) {
  const int lane = threadIdx.x & 63;
  float hv[10], wv[10];
  float pre2 = 0.f;
#pragma unroll
  for (int t = 0; t < 10; ++t) {
    const int j = lane + t * 64;
    hv[t] = (float)h[(size_t)row * 640 + j];
    wv[t] = Hw2[j];
    pre2 += hv[t] * wv[t];
  }
#pragma unroll
  for (int d = 1; d < 64; d <<= 1) pre2 += __shfl_xor(pre2, d, 64);
  const float y = fast_tanh(pre2 + Hb2[0]);
  const float s = 1.f - y * y;
#pragma unroll
  for (int t = 0; t < 10; ++t) {
    const int j = lane + t * 64;
    wout[(size_t)row * 640 + j] = (bf16_t)(s * wv[t] * (1.f - hv[t] * hv[t]));
  }
}

// ---------------------------------------------------------------------------
// L0: inp cvt (1024) + Hw1T (160) + Aw1T (64) + Aw2T (512) + Hw1_bf cvt (160)
//     + zero-out (1024) = 2944 blocks
// ---------------------------------------------------------------------------
__global__ __launch_bounds__(256) void launch0(
    const float* __restrict__ inp, bf16_t* __restrict__ inp_bf,
    const float* __restrict__ Hw1, bf16_t* __restrict__ Hw1T,
    bf16_t* __restrict__ Hw1_bf, const float* __restrict__ Aw1,
    bf16_t* __restrict__ Aw1T, const float* __restrict__ Aw2,
    bf16_t* __restrict__ Aw2T, float* __restrict__ out) {
  __shared__ __align__(16) char smem[4224];
  int b = blockIdx.x;
  if (b < 1024) {
    const int i = b * 256 + threadIdx.x;
    const float4 v = ((const float4*)inp)[i];
    bf16x4_t o = {(bf16_t)v.x, (bf16_t)v.y, (bf16_t)v.z, (bf16_t)v.w};
    ((bf16x4_t*)inp_bf)[i] = o;
  } else if (b < 1184) {
    int s = b - 1024;
    tcvt_body(smem, Hw1, Hw1T, 256, 640, s % 20, s / 20);
  } else if (b < 1248) {
    int s = b - 1184;
    tcvt_body(smem, Aw1, Aw1T, 128, 512, s % 16, s / 16);
  } else if (b < 1760) {
    int s = b - 1248;
    tcvt_body(smem, Aw2, Aw2T, 512, 1024, s % 32, s / 32);
  } else if (b < 1920) {
    const int i = (b - 1760) * 256 + threadIdx.x;
    const float4 v = ((const float4*)Hw1)[i];
    bf16x4_t o = {(bf16_t)v.x, (bf16_t)v.y, (bf16_t)v.z, (bf16_t)v.w};
    ((bf16x4_t*)Hw1_bf)[i] = o;
  } else {
    const int i = (b - 1920) * 256 + threadIdx.x;
    ((float4*)out)[i] = make_float4(0.f, 0.f, 0.f, 0.f);
  }
}

// ---------------------------------------------------------------------------
// L1: Hfwd 64^2 (640) + A1 64^2 (512) + Aw3T tiles [0,512) = 1664 blocks
// ---------------------------------------------------------------------------
__global__ __launch_bounds__(256) void launch1(
    const bf16_t* __restrict__ inp_bf, const bf16_t* __restrict__ Hw1T,
    const float* __restrict__ Hb1, bf16_t* __restrict__ h_bf,
    const bf16_t* __restrict__ Aw1T, const float* __restrict__ Ab1,
    bf16_t* __restrict__ h1_bf, const float* __restrict__ Aw3,
    uint8_t* __restrict__ Aw3T8) {
  __shared__ __align__(16) char smem[SMEM_G64];
  const int b = blockIdx.x;
  if (b < 640) {
    gemm64_body<0>(smem, b % 64, b / 64, inp_bf, 256, Hw1T, 256, 256, Hb1,
                   h_bf, 640);
  } else if (b < 1152) {
    const int i = b - 640;
    gemm64_body<0>(smem, i % 64, i / 64, inp_bf, 256, Aw1T, 128, 128, Ab1,
                   h1_bf, 512);
  } else {
    aw3t_body(smem, Aw3, Aw3T8, b - 1152);  // tiles 0..511 (rows 0..511)
  }
}

// ---------------------------------------------------------------------------
// L2: A2->fp8 64^2 (1024) + hgrad (1024) + Aw3T tiles [512,1024) = 2560
// ---------------------------------------------------------------------------
__global__ __launch_bounds__(256) void launch2(
    const bf16_t* __restrict__ h1_bf, const bf16_t* __restrict__ Aw2T,
    const float* __restrict__ Ab2, uint8_t* __restrict__ h2_f8,
    const bf16_t* __restrict__ h_bf, const float* __restrict__ Hw2,
    const float* __restrict__ Hb2, bf16_t* __restrict__ w_bf,
    const float* __restrict__ Aw3, uint8_t* __restrict__ Aw3T8) {
  __shared__ __align__(16) char smem[SMEM_G64];
  const int b = blockIdx.x;
  if (b < 1024) {
    gemm64_body<3>(smem, b % 64, b / 64, h1_bf, 512, Aw2T, 512, 512, Ab2,
                   h2_f8, 1024);
  } else if (b < 2048) {
    const int row = (b - 1024) * 4 + (threadIdx.x >> 6);
    hgrad_row(row, h_bf, Hw2, Hb2, w_bf);
  } else {
    aw3t_body(smem, Aw3, Aw3T8, 512 + (b - 2048));  // tiles 512..1023
  }
}

// ---------------------------------------------------------------------------
// L3 (512 threads): Hbwd 64^2 8-wave (256) + A3 8-wave tbuf (2048) = 2304.
// A3 swizzle: hardware XCD = blockIdx%8; each XCD owns a contiguous 16-wide
// by range (B working set 2MB -> L2-resident), bx varies slowest.
// ---------------------------------------------------------------------------
__global__ __launch_bounds__(512, 4) void launch3(
    const bf16_t* __restrict__ w_bf, const bf16_t* __restrict__ Hw1_bf,
    float* __restrict__ out, const uint8_t* __restrict__ h2_f8,
    const uint8_t* __restrict__ Aw3T8, const float* __restrict__ Ab3,
    const float* __restrict__ uvec) {
  __shared__ __align__(16) char smem[SMEM3_BYTES];
  const int b = blockIdx.x;
  if (b < 256) {
    hbwd64_body(smem, b % 64, b / 64, w_bf, 640, Hw1_bf, 640, 640, out, 256);
  } else {
    const int p = b - 256;                      // 0..2047; hw XCD = p % 8
    const int by = (p & 7) * 16 + ((p >> 3) & 15);  // 0..127
    const int bx = p >> 7;                      // 0..15
    a3_body(smem, bx, by, h2_f8, Aw3T8, out, Ab3, uvec);
  }
}

// ---------------------------------------------------------------------------
extern "C" void kernel_launch(void* const* d_in, const int* in_sizes, int n_in,
                              void* d_out, int out_size, void* d_ws,
                              size_t ws_size, hipStream_t stream) {
  (void)in_sizes; (void)n_in; (void)out_size; (void)ws_size;
  const float* inp = (const float*)d_in[1];
  const float* Hw1 = (const float*)d_in[2];
  const float* Hb1 = (const float*)d_in[3];
  const float* Hw2 = (const float*)d_in[4];
  const float* Hb2 = (const float*)d_in[5];
  const float* Aw1 = (const float*)d_in[6];
  const float* Ab1 = (const float*)d_in[7];
  const float* Aw2 = (const float*)d_in[8];
  const float* Ab2 = (const float*)d_in[9];
  const float* Aw3 = (const float*)d_in[10];
  const float* Ab3 = (const float*)d_in[11];
  const float* u = (const float*)d_in[12];
  float* out = (float*)d_out;

  char* ws = (char*)d_ws;
  bf16_t* inp_bf = (bf16_t*)ws;   ws += (size_t)NROW * 256 * 2;
  bf16_t* Hw1_bf = (bf16_t*)ws;   ws += (size_t)256 * 640 * 2;
  bf16_t* Hw1T = (bf16_t*)ws;     ws += (size_t)640 * 256 * 2;
  bf16_t* Aw1T = (bf16_t*)ws;     ws += (size_t)512 * 128 * 2;
  bf16_t* Aw2T = (bf16_t*)ws;     ws += (size_t)1024 * 512 * 2;
  uint8_t* Aw3T8 = (uint8_t*)ws;  ws += (size_t)16384 * 1024;
  bf16_t* h_bf = (bf16_t*)ws;     ws += (size_t)NROW * 640 * 2;
  bf16_t* w_bf = (bf16_t*)ws;     ws += (size_t)NROW * 640 * 2;
  bf16_t* h1_bf = (bf16_t*)ws;    ws += (size_t)NROW * 512 * 2;
  uint8_t* h2_f8 = (uint8_t*)ws;  ws += (size_t)NROW * 1024;

  launch0<<<2944, 256, 0, stream>>>(inp, inp_bf, Hw1, Hw1T, Hw1_bf, Aw1, Aw1T,
                                    Aw2, Aw2T, out);
  launch1<<<1664, 256, 0, stream>>>(inp_bf, Hw1T, Hb1, h_bf, Aw1T, Ab1, h1_bf,
                                    Aw3, Aw3T8);
  launch2<<<2560, 256, 0, stream>>>(h1_bf, Aw2T, Ab2, h2_f8, h_bf, Hw2, Hb2,
                                    w_bf, Aw3, Aw3T8);
  launch3<<<2304, 512, 0, stream>>>(w_bf, Hw1_bf, out, h2_f8, Aw3T8, Ab3, u);
}

// Round 5
// 229.719 us; speedup vs baseline: 1.0390x; 1.0390x over previous
//
#include <hip/hip_runtime.h>
#include <hip/hip_bf16.h>
#include <cstdint>

// ---------------------------------------------------------------------------
// Hamilton_V5  R14:
//  - A3 wave tile 64x64 -> 64x128 (acc[2][4]): 12 ds_read_b128 per 8 mfma
//    (ratio 1.5 vs 2.0). LDS pipe was the saturated pipe (59% of cycles,
//    incl. the 4cy/read conflict tax); MFMA only 27%.
//    BM=256, BN=256, grid 16x64 = 1024 blocks; ~195 VGPR -> 2 waves/SIMD ->
//    1 block/CU (accepted: R11's triple-buffer + counted vmcnt(4) keeps the
//    8 waves overlapped). __launch_bounds__(512,2) caps allocator at 256.
//  - Each 256-col by'-tile reduces to out cols {128+2by', 128+2by'+1}.
//  - L0/L1/L2 byte-identical to R13 = control.
// ---------------------------------------------------------------------------

typedef __bf16 bf16_t;
typedef __bf16 bf16x4_t __attribute__((ext_vector_type(4)));
typedef __bf16 bf16x8_t __attribute__((ext_vector_type(8)));
typedef float f32x4_t __attribute__((ext_vector_type(4)));
typedef float f32x16_t __attribute__((ext_vector_type(16)));
typedef int intx4_t __attribute__((ext_vector_type(4)));
typedef int intx8_t __attribute__((ext_vector_type(8)));

#define DIMD 128
#define NROW 4096
#define SMEM_G64 24576     // gemm64 3-buf (3*4096*2) ; aw3t 16896 fits
#define SMEM3_BYTES 98304  // a3: 3*(16384 A + 16384 B)

// branchless tanh: t=2^(2x*log2e); tanh=1-2/(t+1).
__device__ __forceinline__ float fast_tanh(float x) {
  float t = __builtin_amdgcn_exp2f(x * 2.8853900817779268f);
  return 1.f - 2.f * __builtin_amdgcn_rcpf(t + 1.f);
}

// f32 -> fp8 e4m3 (OCP), RNE+sat via HW cvt
__device__ __forceinline__ uint8_t to_fp8(float x) {
  return (uint8_t)(__builtin_amdgcn_cvt_pk_fp8_f32(x, x, 0, false) & 0xff);
}

// pack 4 f32 -> 4 fp8 bytes (byte0=a .. byte3=d) via 2 HW cvt_pk
__device__ __forceinline__ uint32_t pk4_fp8(float a, float b, float c,
                                            float d) {
  uint32_t lo = (uint32_t)__builtin_amdgcn_cvt_pk_fp8_f32(a, b, 0, false);
  return (uint32_t)__builtin_amdgcn_cvt_pk_fp8_f32(c, d, lo, true);
}

// async global->LDS, 16B per lane; LDS dest = wave-uniform base + lane*16
__device__ __forceinline__ void g2l16(const void* gp, void* lp) {
  __builtin_amdgcn_global_load_lds(
      reinterpret_cast<__attribute__((address_space(1))) void*>(
          reinterpret_cast<uintptr_t>(gp)),
      reinterpret_cast<__attribute__((address_space(3))) void*>(
          reinterpret_cast<uintptr_t>(lp)),
      16, 0, 0);
}

// DPP accumulating add (VALU pipe -- no LDS). bound_ctrl=1 => 0-fill.
template <int CTRL>
__device__ __forceinline__ float dpp_addf(float v) {
  return v + __int_as_float(__builtin_amdgcn_update_dpp(
                 0, __float_as_int(v), CTRL, 0xf, 0xf, true));
}
// sum over each 32-lane half; result in lane 31 (half 0) / lane 63 (half 1).
__device__ __forceinline__ float dpp_sum32(float v) {
  v = dpp_addf<0x111>(v);  // row_shr:1
  v = dpp_addf<0x112>(v);  // row_shr:2
  v = dpp_addf<0x114>(v);  // row_shr:4
  v = dpp_addf<0x118>(v);  // row_shr:8  -> lane15/31/47/63 = row sums
  v = dpp_addf<0x142>(v);  // row_bcast15 -> lane31/63 = 32-lane sums
  return v;
}

// ---------------------------------------------------------------------------
// bf16 GEMM, 64x64 tile, BK=32, 4 waves 2x2 (each 32x32 = 2x2 mfma 16x16x32).
// Triple-buffered LDS, depth-2 prefetch, counted vmcnt(2) per step.
// LDS swizzle: row r's 16B k-chunk kc at slot kc ^ ((r>>1)&3).
// EPI 0: bf16 tanh(C+b); EPI 3: fp8 x64.  (256-thread launches only.)
// ---------------------------------------------------------------------------
template <int EPI>
__device__ __forceinline__ void gemm64_body(char* smem, int bx, int by,
                                            const bf16_t* A, int lda,
                                            const bf16_t* B, int ldb, int K,
                                            const float* bias, void* outp,
                                            int ldo) {
  constexpr int BK = 32;
  bf16_t* As = (bf16_t*)smem;   // 3 x 64*32
  bf16_t* Bs = As + 3 * 2048;   // 3 x 64*32
  const int NT = K / BK;

  const int m0 = bx * 64;
  const int n0 = by * 64;
  const int tid = threadIdx.x;
  const int wave = tid >> 6;
  const int lane = tid & 63;
  const int wm = wave >> 1;
  const int wn = wave & 1;

  const int sr = lane >> 2;
  const int sk = (((lane & 3) ^ ((sr >> 1) & 3)) * 8);
  const int fr = lane & 15;
  const int fk = (((lane >> 4) ^ ((fr >> 1) & 3)) * 8);
  const int rb = wave * 16;  // each wave stages 16 rows of A and B

  const bf16_t* Ag = A + (size_t)(m0 + rb + sr) * lda + sk;
  const bf16_t* Bg = B + (size_t)(n0 + rb + sr) * ldb + sk;

#define G64_STAGE(buf, k0)                              \
  do {                                                  \
    g2l16(Ag + (k0), As + (buf) * 2048 + rb * BK);      \
    g2l16(Bg + (k0), Bs + (buf) * 2048 + rb * BK);      \
  } while (0)

  f32x4_t acc[2][2] = {};

  G64_STAGE(0, 0);
  G64_STAGE(1, BK);
  asm volatile("s_waitcnt vmcnt(2)" ::: "memory");
  __builtin_amdgcn_s_barrier();
  asm volatile("" ::: "memory");

  for (int t = 0; t < NT; ++t) {
    if (t + 2 < NT) G64_STAGE((t + 2) % 3, (t + 2) * BK);
    const bf16_t* Ab = As + (t % 3) * 2048;
    const bf16_t* Bb = Bs + (t % 3) * 2048;

    bf16x8_t af[2], bb[2];
#pragma unroll
    for (int u = 0; u < 2; ++u) {
      af[u] = *(const bf16x8_t*)(Ab + (wm * 32 + u * 16 + fr) * BK + fk);
      bb[u] = *(const bf16x8_t*)(Bb + (wn * 32 + u * 16 + fr) * BK + fk);
    }
#pragma unroll
    for (int i = 0; i < 2; ++i)
#pragma unroll
      for (int j = 0; j < 2; ++j)
        acc[i][j] = __builtin_amdgcn_mfma_f32_16x16x32_bf16(af[i], bb[j],
                                                            acc[i][j], 0, 0, 0);
    if (t < NT - 1) {
      if (t + 2 < NT)
        asm volatile("s_waitcnt vmcnt(2)" ::: "memory");
      else
        asm volatile("s_waitcnt vmcnt(0)" ::: "memory");
      __builtin_amdgcn_s_barrier();
      asm volatile("" ::: "memory");
    }
  }
#undef G64_STAGE

  // C/D layout (m89): col = lane&15, row = (lane>>4)*4 + reg
#pragma unroll
  for (int i = 0; i < 2; ++i) {
    const int row = m0 + wm * 32 + i * 16 + (lane >> 4) * 4;
#pragma unroll
    for (int j = 0; j < 2; ++j) {
      const int col = n0 + wn * 32 + j * 16 + fr;
      if constexpr (EPI == 0) {
        bf16_t* O = (bf16_t*)outp;
        const float b = bias[col];
#pragma unroll
        for (int r = 0; r < 4; ++r)
          O[(size_t)(row + r) * ldo + col] = (bf16_t)fast_tanh(acc[i][j][r] + b);
      } else {  // EPI 3
        uint8_t* O = (uint8_t*)outp;
        const float b = bias[col];
#pragma unroll
        for (int r = 0; r < 4; ++r)
          O[(size_t)(row + r) * ldo + col] =
              to_fp8(64.f * fast_tanh(acc[i][j][r] + b));
      }
    }
  }
}

// ---------------------------------------------------------------------------
// Hbwd bf16 GEMM for 512-thread launch: 64x64 tile, BK=32, 8 waves arranged
// 2x4; per-wave 32x16 = 2x1 mfma 16x16x32.  dx store / dv atomicAdd(-C).
// Triple-buffer/counted-vmcnt pipeline (1 stage op per wave).
// ---------------------------------------------------------------------------
__device__ __forceinline__ void hbwd64_body(char* smem, int bx, int by,
                                            const bf16_t* A, int lda,
                                            const bf16_t* B, int ldb, int K,
                                            float* out, int ldo) {
  constexpr int BK = 32;
  bf16_t* As = (bf16_t*)smem;  // 3 x 64*32
  bf16_t* Bs = As + 3 * 2048;
  const int NT = K / BK;  // 20

  const int m0 = bx * 64;
  const int n0 = by * 64;
  const int tid = threadIdx.x;
  const int wave = tid >> 6;  // 0..7
  const int lane = tid & 63;
  const int wm = wave >> 2;   // 0..1
  const int wn = wave & 3;    // 0..3

  const int sr = lane >> 2;
  const int sk = (((lane & 3) ^ ((sr >> 1) & 3)) * 8);
  const int fr = lane & 15;
  const int fk = (((lane >> 4) ^ ((fr >> 1) & 3)) * 8);

  // waves 0..3 stage A rows, 4..7 stage B rows (1 g2l16 per wave per step)
  const int rbs = (wave & 3) * 16;
  const bf16_t* Sg = (wave < 4) ? A + (size_t)(m0 + rbs + sr) * lda + sk
                                : B + (size_t)(n0 + rbs + sr) * ldb + sk;
  bf16_t* Sl = ((wave < 4) ? As : Bs) + rbs * BK;

  f32x4_t acc[2] = {};

  g2l16(Sg, Sl);
  g2l16(Sg + BK, Sl + 2048);
  asm volatile("s_waitcnt vmcnt(1)" ::: "memory");
  __builtin_amdgcn_s_barrier();
  asm volatile("" ::: "memory");

  for (int t = 0; t < NT; ++t) {
    if (t + 2 < NT) g2l16(Sg + (t + 2) * BK, Sl + ((t + 2) % 3) * 2048);
    const bf16_t* Ab = As + (t % 3) * 2048;
    const bf16_t* Bb = Bs + (t % 3) * 2048;

    const bf16x8_t bb = *(const bf16x8_t*)(Bb + (wn * 16 + fr) * BK + fk);
#pragma unroll
    for (int u = 0; u < 2; ++u) {
      const bf16x8_t af =
          *(const bf16x8_t*)(Ab + (wm * 32 + u * 16 + fr) * BK + fk);
      acc[u] = __builtin_amdgcn_mfma_f32_16x16x32_bf16(af, bb, acc[u], 0, 0, 0);
    }
    if (t < NT - 1) {
      if (t + 2 < NT)
        asm volatile("s_waitcnt vmcnt(1)" ::: "memory");
      else
        asm volatile("s_waitcnt vmcnt(0)" ::: "memory");
      __builtin_amdgcn_s_barrier();
      asm volatile("" ::: "memory");
    }
  }

  // C/D layout (m89): col = lane&15, row = (lane>>4)*4 + reg
  const bool dx = (n0 < DIMD);
  const int col = n0 + wn * 16 + fr;
#pragma unroll
  for (int t = 0; t < 2; ++t) {
    const int row = m0 + wm * 32 + t * 16 + (lane >> 4) * 4;
#pragma unroll
    for (int r = 0; r < 4; ++r) {
      const size_t idx = (size_t)(row + r) * ldo + col;
      if (dx) out[idx] = acc[t][r];
      else atomicAdd(&out[idx], -acc[t][r]);  // dv_H shares with dvA
    }
  }
}

// ---------------------------------------------------------------------------
// A3 fused GEMM, MX-fp8, R14: 512 threads / 8 waves, BM=256, BN=256, BK=64.
// Wave grid 4x2: each wave 64x128 via 2x4 mfma 32x32x64 (acc[2][4] f32x16).
// 12 ds_read_b128 -> 8 mfma per wave-tile (ratio 1.5, was 2.0).
// Triple-buffered LDS, depth-2 prefetch, counted vmcnt(4) (4 stage ops/wave).
// Each by-tile (256 cols) reduces to out cols {128+2by, 128+2by+1}.
// ---------------------------------------------------------------------------
__device__ __forceinline__ void a3_body(char* smem, int bx, int by,
                                        const uint8_t* A, const uint8_t* B,
                                        float* out, const float* ab3,
                                        const float* uvec) {
  constexpr int BK = 64, K = 1024, NT = K / BK;  // NT = 16
  uint8_t* As = (uint8_t*)smem;             // 3 x 256*64 = 49152
  uint8_t* Bs = As + 49152;                 // 3 x 256*64 = 49152

  const int m0 = bx * 256;
  const int n0 = by * 256;
  const int tid = threadIdx.x;
  const int wave = tid >> 6;  // 0..7
  const int lane = tid & 63;
  const int wm = wave >> 1;   // 0..3 : 64-row strip
  const int wn = wave & 1;    // 0..1 : 128-col strip

  const int sr = lane >> 2;
  const int sk = ((lane & 3) ^ ((sr >> 1) & 3)) * 16;

  const int rl = lane & 31;
  const int w = (rl >> 1) & 3;
  const int c0 = lane >> 5;
  const int sLo = ((2 * c0) ^ w) * 16;
  const int sHi = ((2 * c0 + 1) ^ w) * 16;

  f32x16_t acc[2][4] = {};

  // per K-step: each wave stages 2 A-chunks + 2 B-chunks (16 rows each)
  // = 4 VMEM ops per wave per tile (vmcnt counts these).
#define A3_STAGE(buf, k0)                                                     \
  do {                                                                        \
    uint8_t* Ad = As + (buf) * 16384;                                         \
    uint8_t* Bd = Bs + (buf) * 16384;                                         \
    _Pragma("unroll") for (int t_ = 0; t_ < 2; ++t_) {                        \
      const int rb_ = wave * 32 + t_ * 16;                                    \
      g2l16(A + (size_t)(m0 + rb_ + sr) * K + ((k0) + sk), Ad + rb_ * BK);    \
      g2l16(B + (size_t)(n0 + rb_ + sr) * K + ((k0) + sk), Bd + rb_ * BK);    \
    }                                                                         \
  } while (0)

  A3_STAGE(0, 0);
  A3_STAGE(1, BK);
  asm volatile("s_waitcnt vmcnt(4)" ::: "memory");
  __builtin_amdgcn_s_barrier();
  asm volatile("" ::: "memory");

  int cur = 0, pre = 2;  // tile t reads buf (t%3); prefetch writes (t+2)%3
#pragma unroll 1
  for (int t = 0; t < NT; ++t) {
    if (t + 2 < NT) A3_STAGE(pre, (t + 2) * BK);
    const uint8_t* Ab = As + cur * 16384;
    const uint8_t* Bb = Bs + cur * 16384;

    __builtin_amdgcn_s_setprio(1);
    intx8_t bfr[4];
#pragma unroll
    for (int j = 0; j < 4; ++j) {
      const int rb2 = (wn * 128 + j * 32 + rl) * BK;
      intx4_t lob = *(const intx4_t*)(Bb + rb2 + sLo);
      intx4_t hib = *(const intx4_t*)(Bb + rb2 + sHi);
      bfr[j] = __builtin_shufflevector(lob, hib, 0, 1, 2, 3, 4, 5, 6, 7);
    }
#pragma unroll
    for (int i = 0; i < 2; ++i) {
      const int ra = (wm * 64 + i * 32 + rl) * BK;
      intx4_t lo = *(const intx4_t*)(Ab + ra + sLo);
      intx4_t hi = *(const intx4_t*)(Ab + ra + sHi);
      intx8_t af = __builtin_shufflevector(lo, hi, 0, 1, 2, 3, 4, 5, 6, 7);
#pragma unroll
      for (int j = 0; j < 4; ++j)
        acc[i][j] = __builtin_amdgcn_mfma_scale_f32_32x32x64_f8f6f4(
            af, bfr[j], acc[i][j], 0, 0, 0, 0x79797979, 0, 0x79797979);
    }
    __builtin_amdgcn_s_setprio(0);

    if (t < NT - 1) {
      // keep the t+2 stage (4 ops) in flight across the barrier.
      if (t + 2 < NT)
        asm volatile("s_waitcnt vmcnt(4)" ::: "memory");
      else
        asm volatile("s_waitcnt vmcnt(0)" ::: "memory");
      __builtin_amdgcn_s_barrier();
      asm volatile("" ::: "memory");
    }
    cur = (cur == 2) ? 0 : cur + 1;
    pre = (pre == 2) ? 0 : pre + 1;
  }
#undef A3_STAGE

  // epilogue: no LDS. C/D: col = lane&31, row = (reg&3)+8*(reg>>2)+4*(lane>>5)
  // wave's 128 cols (j*32+rl) are one full u-period -> ONE out column:
  //   out col = 128 + 2*by + wn ; u-index = j*32+rl ; ab3 = n0+wn*128+j*32+rl
  const int q = lane >> 5;
  float uu[4], b3[4];
#pragma unroll
  for (int j = 0; j < 4; ++j) {
    uu[j] = uvec[j * 32 + rl];
    b3[j] = ab3[n0 + wn * 128 + j * 32 + rl];
  }
  const int ocol = 128 + 2 * by + wn;
#pragma unroll
  for (int i = 0; i < 2; ++i) {
    float s16[16];
#pragma unroll
    for (int r = 0; r < 16; ++r) {
      float s = 0.f;
#pragma unroll
      for (int j = 0; j < 4; ++j) s += fast_tanh(acc[i][j][r] + b3[j]) * uu[j];
      s16[r] = s;
    }
#pragma unroll
    for (int r = 0; r < 16; ++r) s16[r] = dpp_sum32(s16[r]);
    if (rl == 31) {  // lanes 31 and 63 hold the two q-half sums (distinct rows)
      const int rowb = m0 + wm * 64 + i * 32 + 4 * q;
#pragma unroll
      for (int r = 0; r < 16; ++r)
        atomicAdd(&out[(size_t)(rowb + (r & 3) + 8 * (r >> 2)) * 256 + ocol],
                  s16[r]);
    }
  }
}

// ---------------------------------------------------------------------------
// transposes / cvt helpers
// ---------------------------------------------------------------------------
__device__ __forceinline__ void tcvt_body(char* smem, const float* in,
                                          bf16_t* out, int R, int C, int bx,
                                          int by) {
  float(*t)[33] = (float(*)[33])smem;  // 4224 B
  const int c0 = bx * 32;
  const int r0 = by * 32;
  const int tx = threadIdx.x & 31;
  const int ty = threadIdx.x >> 5;
#pragma unroll
  for (int k = 0; k < 4; ++k)
    t[ty + k * 8][tx] = in[(size_t)(r0 + ty + k * 8) * C + c0 + tx];
  __syncthreads();
#pragma unroll
  for (int k = 0; k < 4; ++k)
    out[(size_t)(c0 + ty + k * 8) * R + r0 + tx] = (bf16_t)t[tx][ty + k * 8];
}

// Aw3 (1024 x 16384) -> fp8 x64, transposed (16384 x 1024).
// 128x128 tile per block (1024 blocks total), float4 reads, cvt_pk packing,
// u32-transposed LDS [128][33], 128B-coalesced u32 stores.
__device__ __forceinline__ void aw3t_body(char* smem, const float* Aw3,
                                          uint8_t* Aw3T8, int b) {
  uint32_t(*T)[33] = (uint32_t(*)[33])smem;  // 16896 B
  const int ct = b & 127;
  const int rt = b >> 7;
  const size_t c0 = (size_t)ct * 128;
  const int r0 = rt * 128;
  const int tx = threadIdx.x & 31;  // col-chunk (4 f32)
  const int g = threadIdx.x >> 5;   // 0..7 row-group
#pragma unroll
  for (int k = 0; k < 4; ++k) {
    const int rr = r0 + 4 * g + 32 * k;
    const float4 v0 = *(const float4*)(Aw3 + (size_t)(rr + 0) * 16384 + c0 + 4 * tx);
    const float4 v1 = *(const float4*)(Aw3 + (size_t)(rr + 1) * 16384 + c0 + 4 * tx);
    const float4 v2 = *(const float4*)(Aw3 + (size_t)(rr + 2) * 16384 + c0 + 4 * tx);
    const float4 v3 = *(const float4*)(Aw3 + (size_t)(rr + 3) * 16384 + c0 + 4 * tx);
    const int r4 = g + 8 * k;  // row/4 within tile
    T[4 * tx + 0][r4] = pk4_fp8(64.f * v0.x, 64.f * v1.x, 64.f * v2.x, 64.f * v3.x);
    T[4 * tx + 1][r4] = pk4_fp8(64.f * v0.y, 64.f * v1.y, 64.f * v2.y, 64.f * v3.y);
    T[4 * tx + 2][r4] = pk4_fp8(64.f * v0.z, 64.f * v1.z, 64.f * v2.z, 64.f * v3.z);
    T[4 * tx + 3][r4] = pk4_fp8(64.f * v0.w, 64.f * v1.w, 64.f * v2.w, 64.f * v3.w);
  }
  __syncthreads();
#pragma unroll
  for (int k2 = 0; k2 < 16; ++k2) {
    const int cc = g + 8 * k2;  // output row (Aw3 col)
    *(uint32_t*)(Aw3T8 + (c0 + cc) * 1024 + r0 + 4 * tx) = T[cc][tx];
  }
}

// one wave handles one row: pre2 = h.Hw2; w_j = s*Hw2_j*(1-h_j^2)
__device__ __forceinline__ void hgrad_row(int row, const bf16_t* h,
                                          const float* Hw2, const float* Hb2,
                                          bf16_t* wout) {
  const int lane = threadIdx.x & 63;
  float hv[10], wv[10];
  float pre2 = 0.f;
#pragma unroll
  for (int t = 0; t < 10; ++t) {
    const int j = lane + t * 64;
    hv[t] = (float)h[(size_t)row * 640 + j];
    wv[t] = Hw2[j];
    pre2 += hv[t] * wv[t];
  }
#pragma unroll
  for (int d = 1; d < 64; d <<= 1) pre2 += __shfl_xor(pre2, d, 64);
  const float y = fast_tanh(pre2 + Hb2[0]);
  const float s = 1.f - y * y;
#pragma unroll
  for (int t = 0; t < 10; ++t) {
    const int j = lane + t * 64;
    wout[(size_t)row * 640 + j] = (bf16_t)(s * wv[t] * (1.f - hv[t] * hv[t]));
  }
}

// ---------------------------------------------------------------------------
// L0: inp cvt (1024) + Hw1T (160) + Aw1T (64) + Aw2T (512) + Hw1_bf cvt (160)
//     + zero-out (1024) = 2944 blocks
// ---------------------------------------------------------------------------
__global__ __launch_bounds__(256) void launch0(
    const float* __restrict__ inp, bf16_t* __restrict__ inp_bf,
    const float* __restrict__ Hw1, bf16_t* __restrict__ Hw1T,
    bf16_t* __restrict__ Hw1_bf, const float* __restrict__ Aw1,
    bf16_t* __restrict__ Aw1T, const float* __restrict__ Aw2,
    bf16_t* __restrict__ Aw2T, float* __restrict__ out) {
  __shared__ __align__(16) char smem[4224];
  int b = blockIdx.x;
  if (b < 1024) {
    const int i = b * 256 + threadIdx.x;
    const float4 v = ((const float4*)inp)[i];
    bf16x4_t o = {(bf16_t)v.x, (bf16_t)v.y, (bf16_t)v.z, (bf16_t)v.w};
    ((bf16x4_t*)inp_bf)[i] = o;
  } else if (b < 1184) {
    int s = b - 1024;
    tcvt_body(smem, Hw1, Hw1T, 256, 640, s % 20, s / 20);
  } else if (b < 1248) {
    int s = b - 1184;
    tcvt_body(smem, Aw1, Aw1T, 128, 512, s % 16, s / 16);
  } else if (b < 1760) {
    int s = b - 1248;
    tcvt_body(smem, Aw2, Aw2T, 512, 1024, s % 32, s / 32);
  } else if (b < 1920) {
    const int i = (b - 1760) * 256 + threadIdx.x;
    const float4 v = ((const float4*)Hw1)[i];
    bf16x4_t o = {(bf16_t)v.x, (bf16_t)v.y, (bf16_t)v.z, (bf16_t)v.w};
    ((bf16x4_t*)Hw1_bf)[i] = o;
  } else {
    const int i = (b - 1920) * 256 + threadIdx.x;
    ((float4*)out)[i] = make_float4(0.f, 0.f, 0.f, 0.f);
  }
}

// ---------------------------------------------------------------------------
// L1: Hfwd 64^2 (640) + A1 64^2 (512) + Aw3T tiles [0,512) = 1664 blocks
// ---------------------------------------------------------------------------
__global__ __launch_bounds__(256) void launch1(
    const bf16_t* __restrict__ inp_bf, const bf16_t* __restrict__ Hw1T,
    const float* __restrict__ Hb1, bf16_t* __restrict__ h_bf,
    const bf16_t* __restrict__ Aw1T, const float* __restrict__ Ab1,
    bf16_t* __restrict__ h1_bf, const float* __restrict__ Aw3,
    uint8_t* __restrict__ Aw3T8) {
  __shared__ __align__(16) char smem[SMEM_G64];
  const int b = blockIdx.x;
  if (b < 640) {
    gemm64_body<0>(smem, b % 64, b / 64, inp_bf, 256, Hw1T, 256, 256, Hb1,
                   h_bf, 640);
  } else if (b < 1152) {
    const int i = b - 640;
    gemm64_body<0>(smem, i % 64, i / 64, inp_bf, 256, Aw1T, 128, 128, Ab1,
                   h1_bf, 512);
  } else {
    aw3t_body(smem, Aw3, Aw3T8, b - 1152);  // tiles 0..511
  }
}

// ---------------------------------------------------------------------------
// L2: A2->fp8 64^2 (1024) + hgrad (1024) + Aw3T tiles [512,1024) = 2560
// ---------------------------------------------------------------------------
__global__ __launch_bounds__(256) void launch2(
    const bf16_t* __restrict__ h1_bf, const bf16_t* __restrict__ Aw2T,
    const float* __restrict__ Ab2, uint8_t* __restrict__ h2_f8,
    const bf16_t* __restrict__ h_bf, const float* __restrict__ Hw2,
    const float* __restrict__ Hb2, bf16_t* __restrict__ w_bf,
    const float* __restrict__ Aw3, uint8_t* __restrict__ Aw3T8) {
  __shared__ __align__(16) char smem[SMEM_G64];
  const int b = blockIdx.x;
  if (b < 1024) {
    gemm64_body<3>(smem, b % 64, b / 64, h1_bf, 512, Aw2T, 512, 512, Ab2,
                   h2_f8, 1024);
  } else if (b < 2048) {
    const int row = (b - 1024) * 4 + (threadIdx.x >> 6);
    hgrad_row(row, h_bf, Hw2, Hb2, w_bf);
  } else {
    aw3t_body(smem, Aw3, Aw3T8, 512 + (b - 2048));  // tiles 512..1023
  }
}

// ---------------------------------------------------------------------------
// L3 (512 threads): Hbwd 64^2 8-wave (256) + A3 8-wave BN=256 (1024) = 1280.
// A3 swizzle: hardware XCD = p%8; each XCD owns a contiguous 8-wide by range
// (B working set 8 x 256KB = 2MB -> L2-resident), bx varies slowest.
// ---------------------------------------------------------------------------
__global__ __launch_bounds__(512, 2) void launch3(
    const bf16_t* __restrict__ w_bf, const bf16_t* __restrict__ Hw1_bf,
    float* __restrict__ out, const uint8_t* __restrict__ h2_f8,
    const uint8_t* __restrict__ Aw3T8, const float* __restrict__ Ab3,
    const float* __restrict__ uvec) {
  __shared__ __align__(16) char smem[SMEM3_BYTES];
  const int b = blockIdx.x;
  if (b < 256) {
    hbwd64_body(smem, b % 64, b / 64, w_bf, 640, Hw1_bf, 640, 640, out, 256);
  } else {
    const int p = b - 256;                         // 0..1023; hw XCD = p % 8
    const int by = (p & 7) * 8 + ((p >> 3) & 7);   // 0..63
    const int bx = p >> 6;                         // 0..15
    a3_body(smem, bx, by, h2_f8, Aw3T8, out, Ab3, uvec);
  }
}

// ---------------------------------------------------------------------------
extern "C" void kernel_launch(void* const* d_in, const int* in_sizes, int n_in,
                              void* d_out, int out_size, void* d_ws,
                              size_t ws_size, hipStream_t stream) {
  (void)in_sizes; (void)n_in; (void)out_size; (void)ws_size;
  const float* inp = (const float*)d_in[1];
  const float* Hw1 = (const float*)d_in[2];
  const float* Hb1 = (const float*)d_in[3];
  const float* Hw2 = (const float*)d_in[4];
  const float* Hb2 = (const float*)d_in[5];
  const float* Aw1 = (const float*)d_in[6];
  const float* Ab1 = (const float*)d_in[7];
  const float* Aw2 = (const float*)d_in[8];
  const float* Ab2 = (const float*)d_in[9];
  const float* Aw3 = (const float*)d_in[10];
  const float* Ab3 = (const float*)d_in[11];
  const float* u = (const float*)d_in[12];
  float* out = (float*)d_out;

  char* ws = (char*)d_ws;
  bf16_t* inp_bf = (bf16_t*)ws;   ws += (size_t)NROW * 256 * 2;
  bf16_t* Hw1_bf = (bf16_t*)ws;   ws += (size_t)256 * 640 * 2;
  bf16_t* Hw1T = (bf16_t*)ws;     ws += (size_t)640 * 256 * 2;
  bf16_t* Aw1T = (bf16_t*)ws;     ws += (size_t)512 * 128 * 2;
  bf16_t* Aw2T = (bf16_t*)ws;     ws += (size_t)1024 * 512 * 2;
  uint8_t* Aw3T8 = (uint8_t*)ws;  ws += (size_t)16384 * 1024;
  bf16_t* h_bf = (bf16_t*)ws;     ws += (size_t)NROW * 640 * 2;
  bf16_t* w_bf = (bf16_t*)ws;     ws += (size_t)NROW * 640 * 2;
  bf16_t* h1_bf = (bf16_t*)ws;    ws += (size_t)NROW * 512 * 2;
  uint8_t* h2_f8 = (uint8_t*)ws;  ws += (size_t)NROW * 1024;

  launch0<<<2944, 256, 0, stream>>>(inp, inp_bf, Hw1, Hw1T, Hw1_bf, Aw1, Aw1T,
                                    Aw2, Aw2T, out);
  launch1<<<1664, 256, 0, stream>>>(inp_bf, Hw1T, Hb1, h_bf, Aw1T, Ab1, h1_bf,
                                    Aw3, Aw3T8);
  launch2<<<2560, 256, 0, stream>>>(h1_bf, Aw2T, Ab2, h2_f8, h_bf, Hw2, Hb2,
                                    w_bf, Aw3, Aw3T8);
  launch3<<<1280, 512, 0, stream>>>(w_bf, Hw1_bf, out, h2_f8, Aw3T8, Ab3, u);
}